// Round 21
// baseline (329.333 us; speedup 1.0000x reference)
//
#include <hip/hip_runtime.h>
#include <cstdint>
#include <cstddef>

#define N_NODES 4096
#define FEAT 128
#define KCH 4
#define NNZ_CAP (1 << 18)   // col-CSR cap; expected nnz ~65.5K
#define TB2 256             // threads for k_t2 (4 waves -> 8 blocks/CU co-resident)
#define TB3 512             // threads for two-row k_t3 (8 waves; 4 blocks/CU -> 32 waves)
#define T2CAP 2048          // sparse T2 row stride (expected ~273 nnz/row)
#define RSTRIDE 96          // fixed row-list stride (max out-degree ~40 expected)

// OpenBLAS sgemm K-panel boundaries for K=4096, GEMM_Q=384 (level3.c balancing):
// 0,384,768,1152,1536,1920,2304,2688,3072,3456,3776,4096
__device__ __forceinline__ int panel_of(int p) {
    return p < 3456 ? (p / 384) : (p < 3776 ? 9 : 10);
}

// ---- Single adjacency pass (float4 vectorized): per-row ascending column lists
//      (fixed stride) + out-degree + in-degree counts.
__global__ __launch_bounds__(256) void k_adj(const float* __restrict__ adj,
                                             int* __restrict__ deg,
                                             int* __restrict__ rdeg,
                                             int* __restrict__ rcolF) {
    int row = (blockIdx.x * 256 + threadIdx.x) >> 6;   // wave per row
    int lane = threadIdx.x & 63;
    const float4* rowp = (const float4*)(adj + (size_t)row * N_NODES);
    int base = 0;
    for (int it = 0; it < 16; ++it) {
        float4 q = rowp[it * 64 + lane];
        int nib = (q.x != 0.0f) | ((q.y != 0.0f) << 1)
                | ((q.z != 0.0f) << 2) | ((q.w != 0.0f) << 3);
        int cnt = __popc(nib);
        int sc = cnt;                       // inclusive lane prefix of counts
        for (int off = 1; off < 64; off <<= 1) {
            int n = __shfl_up(sc, off);
            if (lane >= off) sc += n;
        }
        int myoff = base + sc - cnt;        // exclusive prefix -> ascending col order
        int x0 = it * 256 + 4 * lane;
        #pragma unroll
        for (int c = 0; c < 4; ++c) {
            if (nib & (1 << c)) {
                if (myoff < RSTRIDE) rcolF[row * RSTRIDE + myoff] = x0 + c;
                atomicAdd(&deg[x0 + c], 1);
                ++myoff;
            }
        }
        base += __shfl(sc, 63);             // wave total
    }
    if (lane == 0) rdeg[row] = (base > RSTRIDE) ? RSTRIDE : base;
}

// ---- Scan: dinv = correctly-rounded fp32 d^-0.5; colptr/colcur from deg.
__global__ __launch_bounds__(1024) void k_scan(const int* __restrict__ deg,
                                               float* __restrict__ dinv,
                                               int* __restrict__ colptr,
                                               int* __restrict__ colcur) {
    __shared__ int wsum[16];
    __shared__ int wbase[16];
    int t = threadIdx.x;
    int lane = t & 63, wv = t >> 6;
    int v[4]; int s = 0;
    for (int c = 0; c < 4; ++c) {
        int idx = t * 4 + c;
        int di = deg[idx];
        v[c] = di;
        s += di;
        float dc = fmaxf((float)di, 1.0f);
        dinv[idx] = (float)(1.0 / sqrt((double)dc));  // correctly-rounded fp32 x^-0.5
    }
    int sc = s;
    for (int off = 1; off < 64; off <<= 1) {
        int n = __shfl_up(sc, off);
        if (lane >= off) sc += n;
    }
    if (lane == 63) wsum[wv] = sc;
    __syncthreads();
    if (t == 0) {
        int b = 0;
        for (int q2 = 0; q2 < 16; ++q2) { wbase[q2] = b; b += wsum[q2]; }
    }
    __syncthreads();
    int base = wbase[wv] + sc - s;   // exclusive prefix over threads
    for (int c = 0; c < 4; ++c) {
        int idx = t * 4 + c;
        colptr[idx] = base; colcur[idx] = base;
        base += v[c];
    }
    if (t == 1023) colptr[N_NODES] = base;
}

// ---- Values pass + fused sW
__global__ __launch_bounds__(256) void k_vals(const float* __restrict__ dinv,
                                              const int* __restrict__ rdeg,
                                              const int* __restrict__ rcolF,
                                              float* __restrict__ rlvalF,
                                              int* __restrict__ colcur,
                                              int* __restrict__ col_i,
                                              float* __restrict__ val,
                                              const float* __restrict__ W,
                                              float* __restrict__ sW) {
    if (blockIdx.x >= N_NODES / 4) {
        int tid = (blockIdx.x - N_NODES / 4) * 256 + threadIdx.x;  // 0..511
        int k = tid >> 7, j = tid & 127;
        float s = 0.f;
        for (int y = 0; y < FEAT; ++y)
            s += fabsf(W[(size_t)j * (KCH * FEAT) + k * FEAT + y]);
        sW[k * FEAT + j] = s;
        return;
    }
    int row = (blockIdx.x * 256 + threadIdx.x) >> 6;
    int lane = threadIdx.x & 63;
    int n = rdeg[row];
    float di = dinv[row];
    for (int e = lane; e < n; e += 64) {
        int x = rcolF[row * RSTRIDE + e];
        float dv = di * dinv[x];
        rlvalF[row * RSTRIDE + e] = -dv;
        int ec = atomicAdd(&colcur[x], 1);
        if (ec < NNZ_CAP) { col_i[ec] = row; val[ec] = dv; }
    }
}

// ---- numpy pairwise_sum over 4096 contiguous fp32 (bitwise replication); needs >=256 thr
__device__ __forceinline__ float np_pairwise_4096(const float* __restrict__ row,
                                                  float* r256, float* leaf,
                                                  float* bc, int t) {
    if (t < 256) {
        int L = t >> 3, j = t & 7;
        const float* p = row + L * 128 + j;
        float a = p[0];
        #pragma unroll
        for (int q = 1; q < 16; ++q) a += p[8 * q];
        r256[t] = a;
    }
    __syncthreads();
    if (t < 32) {
        const float* rr = r256 + t * 8;
        leaf[t] = ((rr[0] + rr[1]) + (rr[2] + rr[3])) + ((rr[4] + rr[5]) + (rr[6] + rr[7]));
    }
    __syncthreads();
    if (t == 0) {
        float v[32];
        #pragma unroll
        for (int q = 0; q < 32; ++q) v[q] = leaf[q];
        #pragma unroll
        for (int w = 16; w >= 1; w >>= 1)
            #pragma unroll
            for (int q = 0; q < 16; ++q)
                if (q < w) v[q] = v[2 * q] + v[2 * q + 1];
        bc[0] = v[0];
    }
    __syncthreads();
    float res = bc[0];
    __syncthreads();
    return res;
}

// ---- k_t2 (R18-proven, bit-exact; TB2=256, no LDS staging, 8 blocks/CU)
__global__ __launch_bounds__(TB2) void k_t2(const int* __restrict__ rdeg,
                                            const int* __restrict__ rcolF,
                                            const float* __restrict__ rlvalF,
                                            unsigned short* __restrict__ t2c,
                                            float* __restrict__ t2v,
                                            int* __restrict__ t2cnt,
                                            float* __restrict__ sA) {
    __shared__ float gp[N_NODES];     // panel partial; later T2 dense row
    __shared__ int   pcol[64];
    __shared__ float pLip[64];
    __shared__ int   pnn[64];
    __shared__ int   ssplit;
    __shared__ float r256[256], leaf[32], bc[1];
    __shared__ int   wtot[4], wbase[4];
    int t = threadIdx.x;
    int i = blockIdx.x;
    int rp = i * RSTRIDE;
    int ol = rdeg[i];                 // out-degree
    int cnt = ol + 1;                 // + diagonal
    if (cnt > 64) cnt = 64;
    if (t == 0) ssplit = 0;
    __syncthreads();
    if (t < ol && rcolF[rp + t] < i) atomicAdd(&ssplit, 1);
    __syncthreads();
    int split = ssplit;
    if (t < cnt) {
        int col; float lip;
        if (t < split)       { col = rcolF[rp + t];     lip = rlvalF[rp + t]; }
        else if (t == split) { col = i;                 lip = 1.0f; }
        else                 { col = rcolF[rp + t - 1]; lip = rlvalF[rp + t - 1]; }
        pcol[t] = col; pLip[t] = lip; pnn[t] = rdeg[col];
    }
    float4* gp4 = (float4*)gp;
    const float4 z4 = make_float4(0.f, 0.f, 0.f, 0.f);
    #pragma unroll
    for (int u2 = 0; u2 < 4; ++u2) gp4[t + u2 * TB2] = z4;
    __syncthreads();
    // ---- s1: build dense L-row(i) in gp, pairwise, sparse-clear
    for (int e = t; e < ol; e += TB2) gp[rcolF[rp + e]] = rlvalF[rp + e];
    if (t == 0) gp[i] = 1.0f;
    __syncthreads();
    float s1 = np_pairwise_4096(gp, r256, leaf, bc, t);
    for (int e = t; e < ol; e += TB2) gp[rcolF[rp + e]] = 0.0f;
    if (t == 0) gp[i] = 0.0f;
    __syncthreads();
    // ---- G = (L@L) row i
    float tot[16];
    #pragma unroll
    for (int u = 0; u < 16; ++u) tot[u] = 0.0f;
    int q = 0;
    while (q < cnt) {
        {
            float lv = pLip[q];
            int p = pcol[q];
            int nn = pnn[q];
            int b = p * RSTRIDE;
            for (int e = t; e < nn; e += TB2)
                gp[rcolF[b + e]] = fmaf(lv, rlvalF[b + e], gp[rcolF[b + e]]);
            if (t == 0) gp[p] = fmaf(lv, 1.0f, gp[p]);   // synthetic diagonal (p not in row)
            __syncthreads();
        }
        ++q;
        if (q == cnt || panel_of(pcol[q]) != panel_of(pcol[q - 1])) {
            #pragma unroll
            for (int u2 = 0; u2 < 4; ++u2) {
                int idx = t + u2 * TB2;
                float4 b = gp4[idx];
                tot[4 * u2 + 0] = tot[4 * u2 + 0] + b.x;
                tot[4 * u2 + 1] = tot[4 * u2 + 1] + b.y;
                tot[4 * u2 + 2] = tot[4 * u2 + 2] + b.z;
                tot[4 * u2 + 3] = tot[4 * u2 + 3] + b.w;
                gp4[idx] = z4;
            }
            __syncthreads();
        }
    }
    // T2 entries fl(2G - I), dense store from registers (x = 4t + 1024*u2 + c)
    #pragma unroll
    for (int u2 = 0; u2 < 4; ++u2) {
        int xb = 4 * t + 1024 * u2;
        float4 v;
        v.x = 2.0f * tot[4 * u2 + 0] - (xb + 0 == i ? 1.0f : 0.0f);
        v.y = 2.0f * tot[4 * u2 + 1] - (xb + 1 == i ? 1.0f : 0.0f);
        v.z = 2.0f * tot[4 * u2 + 2] - (xb + 2 == i ? 1.0f : 0.0f);
        v.w = 2.0f * tot[4 * u2 + 3] - (xb + 3 == i ? 1.0f : 0.0f);
        gp4[t + u2 * TB2] = v;
    }
    __syncthreads();
    float s2 = np_pairwise_4096(gp, r256, leaf, bc, t);
    // ---- sparse emission (ascending col): thread t owns x in [16t, 16t+16)
    float ev[16];
    #pragma unroll
    for (int u2 = 0; u2 < 4; ++u2) {
        float4 e4 = gp4[4 * t + u2];
        ev[4 * u2 + 0] = e4.x; ev[4 * u2 + 1] = e4.y;
        ev[4 * u2 + 2] = e4.z; ev[4 * u2 + 3] = e4.w;
    }
    int cl = 0;
    #pragma unroll
    for (int u = 0; u < 16; ++u) cl += (ev[u] != 0.0f);
    int lane = t & 63, wv = t >> 6;
    int sc = cl;
    for (int off = 1; off < 64; off <<= 1) {
        int n = __shfl_up(sc, off);
        if (lane >= off) sc += n;
    }
    if (lane == 63) wtot[wv] = sc;
    __syncthreads();
    if (t == 0) {
        int b = 0;
        for (int wq = 0; wq < 4; ++wq) { wbase[wq] = b; b += wtot[wq]; }
        t2cnt[i] = (b > T2CAP) ? T2CAP : b;
    }
    __syncthreads();
    int pos = wbase[wv] + sc - cl;
    unsigned short* dstc = t2c + (size_t)i * T2CAP;
    float* dstv = t2v + (size_t)i * T2CAP;
    #pragma unroll
    for (int u = 0; u < 16; ++u) {
        if (ev[u] != 0.0f) {
            if (pos < T2CAP) { dstc[pos] = (unsigned short)(t * 16 + u); dstv[pos] = ev[u]; }
            ++pos;
        }
    }
    if (t == 0) {
        sA[0 * N_NODES + i] = 1.0f;
        sA[1 * N_NODES + i] = s1;
        sA[2 * N_NODES + i] = s2;
    }
}

// ---- k_t3 TWO-ROW (bit-exact): block b owns rows i0=2b, i1=2b+1. Per phase q: scatter
//      row0's T2 source row into gp0 AND row1's into gp1 (disjoint LDS), one barrier;
//      per-row register panel folds at each row's own panel boundary (fold-barrier only
//      when either row folds). Halves barriers/row, doubles loads in flight per phase,
//      keeps 32 waves/CU (4 blocks x 8 waves). Per-row arithmetic sequence identical.
__global__ __launch_bounds__(TB3) void k_t3(const int* __restrict__ rdeg,
                                            const int* __restrict__ rcolF,
                                            const float* __restrict__ rlvalF,
                                            const unsigned short* __restrict__ t2c,
                                            const float* __restrict__ t2v,
                                            const int* __restrict__ t2cnt,
                                            float* __restrict__ sA) {
    __shared__ float gp0[N_NODES];
    __shared__ float gp1[N_NODES];
    __shared__ int   pcol0[64], pcol1[64];
    __shared__ float pLip0[64], pLip1[64];
    __shared__ int   pnn0[64], pnn1[64];
    __shared__ int   ssplit0, ssplit1;
    __shared__ float r256[256], leaf[32], bc[1];
    int t = threadIdx.x;
    int i0 = blockIdx.x * 2, i1 = i0 + 1;
    int rp0 = i0 * RSTRIDE, rp1 = i1 * RSTRIDE;
    int ol0 = rdeg[i0], ol1 = rdeg[i1];
    int cnt0 = ol0 + 1; if (cnt0 > 64) cnt0 = 64;
    int cnt1 = ol1 + 1; if (cnt1 > 64) cnt1 = 64;
    if (t == 0) { ssplit0 = 0; ssplit1 = 0; }
    __syncthreads();
    if (t < ol0 && rcolF[rp0 + t] < i0) atomicAdd(&ssplit0, 1);
    if (t < ol1 && rcolF[rp1 + t] < i1) atomicAdd(&ssplit1, 1);
    __syncthreads();
    int split0 = ssplit0, split1 = ssplit1;
    if (t < cnt0) {
        int col; float lip;
        if (t < split0)       { col = rcolF[rp0 + t];     lip = rlvalF[rp0 + t]; }
        else if (t == split0) { col = i0;                  lip = 1.0f; }
        else                  { col = rcolF[rp0 + t - 1];  lip = rlvalF[rp0 + t - 1]; }
        pcol0[t] = col; pLip0[t] = lip; pnn0[t] = t2cnt[col];
    }
    if (t < cnt1) {
        int col; float lip;
        if (t < split1)       { col = rcolF[rp1 + t];     lip = rlvalF[rp1 + t]; }
        else if (t == split1) { col = i1;                  lip = 1.0f; }
        else                  { col = rcolF[rp1 + t - 1];  lip = rlvalF[rp1 + t - 1]; }
        pcol1[t] = col; pLip1[t] = lip; pnn1[t] = t2cnt[col];
    }
    float4* g04 = (float4*)gp0;
    float4* g14 = (float4*)gp1;
    const float4 z4 = make_float4(0.f, 0.f, 0.f, 0.f);
    #pragma unroll
    for (int u2 = 0; u2 < 2; ++u2) { g04[t + u2 * TB3] = z4; g14[t + u2 * TB3] = z4; }
    __syncthreads();
    float tot0[8], tot1[8];
    #pragma unroll
    for (int u = 0; u < 8; ++u) { tot0[u] = 0.0f; tot1[u] = 0.0f; }
    int mx = (cnt0 > cnt1) ? cnt0 : cnt1;
    int q = 0;
    while (q < mx) {
        if (q < cnt0) {
            float lv = pLip0[q];
            int nn = pnn0[q];
            size_t seg = (size_t)pcol0[q] * T2CAP;
            const unsigned short* spc = t2c + seg;
            const float* spv = t2v + seg;
            for (int e = t; e < nn; e += TB3) {
                int x = spc[e];
                gp0[x] = fmaf(lv, spv[e], gp0[x]);
            }
        }
        if (q < cnt1) {
            float lv = pLip1[q];
            int nn = pnn1[q];
            size_t seg = (size_t)pcol1[q] * T2CAP;
            const unsigned short* spc = t2c + seg;
            const float* spv = t2v + seg;
            for (int e = t; e < nn; e += TB3) {
                int x = spc[e];
                gp1[x] = fmaf(lv, spv[e], gp1[x]);
            }
        }
        __syncthreads();
        bool f0 = (q < cnt0) && (q + 1 == cnt0 || panel_of(pcol0[q + 1]) != panel_of(pcol0[q]));
        bool f1 = (q < cnt1) && (q + 1 == cnt1 || panel_of(pcol1[q + 1]) != panel_of(pcol1[q]));
        if (f0) {
            #pragma unroll
            for (int u2 = 0; u2 < 2; ++u2) {
                int idx = t + u2 * TB3;
                float4 b4 = g04[idx];
                tot0[4 * u2 + 0] = tot0[4 * u2 + 0] + b4.x;
                tot0[4 * u2 + 1] = tot0[4 * u2 + 1] + b4.y;
                tot0[4 * u2 + 2] = tot0[4 * u2 + 2] + b4.z;
                tot0[4 * u2 + 3] = tot0[4 * u2 + 3] + b4.w;
                g04[idx] = z4;
            }
        }
        if (f1) {
            #pragma unroll
            for (int u2 = 0; u2 < 2; ++u2) {
                int idx = t + u2 * TB3;
                float4 b4 = g14[idx];
                tot1[4 * u2 + 0] = tot1[4 * u2 + 0] + b4.x;
                tot1[4 * u2 + 1] = tot1[4 * u2 + 1] + b4.y;
                tot1[4 * u2 + 2] = tot1[4 * u2 + 2] + b4.z;
                tot1[4 * u2 + 3] = tot1[4 * u2 + 3] + b4.w;
                g14[idx] = z4;
            }
        }
        if (f0 || f1) __syncthreads();
        ++q;
    }
    // T3 = fl(2H - T1) for both rows; pairwise each (tree identical to single-row)
    #pragma unroll
    for (int u2 = 0; u2 < 2; ++u2) {
        float4 v0, v1;
        v0.x = 2.0f * tot0[4 * u2 + 0]; v0.y = 2.0f * tot0[4 * u2 + 1];
        v0.z = 2.0f * tot0[4 * u2 + 2]; v0.w = 2.0f * tot0[4 * u2 + 3];
        v1.x = 2.0f * tot1[4 * u2 + 0]; v1.y = 2.0f * tot1[4 * u2 + 1];
        v1.z = 2.0f * tot1[4 * u2 + 2]; v1.w = 2.0f * tot1[4 * u2 + 3];
        g04[t + u2 * TB3] = v0;
        g14[t + u2 * TB3] = v1;
    }
    __syncthreads();
    for (int e = t; e < ol0; e += TB3) {
        int x = rcolF[rp0 + e];
        gp0[x] = gp0[x] - rlvalF[rp0 + e];
    }
    if (t == 0) gp0[i0] = gp0[i0] - 1.0f;
    for (int e = t; e < ol1; e += TB3) {
        int x = rcolF[rp1 + e];
        gp1[x] = gp1[x] - rlvalF[rp1 + e];
    }
    if (t == 0) gp1[i1] = gp1[i1] - 1.0f;
    __syncthreads();
    float s3a = np_pairwise_4096(gp0, r256, leaf, bc, t);
    float s3b = np_pairwise_4096(gp1, r256, leaf, bc, t);
    if (t == 0) {
        sA[3 * N_NODES + i0] = s3a;
        sA[3 * N_NODES + i1] = s3b;
    }
}

// ---- Fused c + M (16 rows/block -> 1024 blocks): c[i,j] = r[i,j]/denom (exact k_c
//      arithmetic: non-contracted, ascending-k mul then add);
//      M_k[i,y] = sum_j c[i,j]*|W[j,k*128+y]|
__global__ __launch_bounds__(256) void k_cm(const float* __restrict__ r,
                                            const float* __restrict__ sA,
                                            const float* __restrict__ sW,
                                            const float* __restrict__ W,
                                            float* __restrict__ M) {
#pragma clang fp contract(off)
    __shared__ float cl[16][FEAT];
    int k = blockIdx.y;
    int ib = blockIdx.x * 16;
    int tx = threadIdx.x;
    int y = tx & 127, half = tx >> 7;
    for (int m = tx; m < 16 * FEAT; m += 256) {
        int i = ib + (m >> 7), j = m & 127;
        float denom = 0.0f;
        #pragma unroll
        for (int k2 = 0; k2 < KCH; ++k2) {
            float p = sA[k2 * N_NODES + i] * sW[k2 * FEAT + j];
            denom = denom + p;
        }
        cl[m >> 7][m & 127] = r[(size_t)i * FEAT + j] / denom;
    }
    __syncthreads();
    float acc[8];
    #pragma unroll
    for (int u = 0; u < 8; ++u) acc[u] = 0.0f;
    for (int j = 0; j < FEAT; ++j) {
        float a = fabsf(W[(size_t)j * (KCH * FEAT) + k * FEAT + y]);
        #pragma unroll
        for (int u = 0; u < 8; ++u) acc[u] += a * cl[half * 8 + u][j];
    }
    #pragma unroll
    for (int u = 0; u < 8; ++u)
        M[(size_t)k * N_NODES * FEAT + (size_t)(ib + half * 8 + u) * FEAT + y] = acc[u];
}

// ---- Horner output chain: out = M0 - M2 + Lap(M1 - 3M3 + Lap(2M2 + Lap(4M3))),
//      Lap(A) = A - D^T A.
// h1: B2 = 2M2 + 4*(M3 - D'M3)
__global__ void k_h1(const int* __restrict__ colptr, const int* __restrict__ col_i,
                     const float* __restrict__ val, const float* __restrict__ M,
                     float* __restrict__ B2) {
    int x = blockIdx.x * 2 + (threadIdx.x >> 7);
    int y = threadIdx.x & 127;
    const float* M2 = M + (size_t)2 * N_NODES * FEAT;
    const float* M3 = M + (size_t)3 * N_NODES * FEAT;
    int e0 = colptr[x], e1 = colptr[x + 1];
    if (e1 > NNZ_CAP) e1 = NNZ_CAP;
    float g = 0.0f;
    for (int e = e0; e < e1; ++e)
        g += val[e] * M3[(size_t)col_i[e] * FEAT + y];
    size_t o = (size_t)x * FEAT + y;
    B2[o] = 2.0f * M2[o] + 4.0f * (M3[o] - g);
}

// h2: B3 = (M1 - 3M3) + (B2 - D'B2)
__global__ void k_h2(const int* __restrict__ colptr, const int* __restrict__ col_i,
                     const float* __restrict__ val, const float* __restrict__ M,
                     const float* __restrict__ B2, float* __restrict__ B3) {
    int x = blockIdx.x * 2 + (threadIdx.x >> 7);
    int y = threadIdx.x & 127;
    const float* M1 = M + (size_t)N_NODES * FEAT;
    const float* M3 = M + (size_t)3 * N_NODES * FEAT;
    int e0 = colptr[x], e1 = colptr[x + 1];
    if (e1 > NNZ_CAP) e1 = NNZ_CAP;
    float g = 0.0f;
    for (int e = e0; e < e1; ++e)
        g += val[e] * B2[(size_t)col_i[e] * FEAT + y];
    size_t o = (size_t)x * FEAT + y;
    B3[o] = (M1[o] - 3.0f * M3[o]) + (B2[o] - g);
}

// h3: out = (M0 - M2) + (B3 - D'B3)
__global__ void k_h3(const int* __restrict__ colptr, const int* __restrict__ col_i,
                     const float* __restrict__ val, const float* __restrict__ M,
                     const float* __restrict__ B3, float* __restrict__ out) {
    int x = blockIdx.x * 2 + (threadIdx.x >> 7);
    int y = threadIdx.x & 127;
    const float* M0 = M;
    const float* M2 = M + (size_t)2 * N_NODES * FEAT;
    int e0 = colptr[x], e1 = colptr[x + 1];
    if (e1 > NNZ_CAP) e1 = NNZ_CAP;
    float g = 0.0f;
    for (int e = e0; e < e1; ++e)
        g += val[e] * B3[(size_t)col_i[e] * FEAT + y];
    size_t o = (size_t)x * FEAT + y;
    out[o] = (M0[o] - M2[o]) + (B3[o] - g);
}

extern "C" void kernel_launch(void* const* d_in, const int* in_sizes, int n_in,
                              void* d_out, int out_size, void* d_ws, size_t ws_size,
                              hipStream_t stream) {
    const float* r   = (const float*)d_in[1];
    const float* adj = (const float*)d_in[2];
    const float* W   = (const float*)d_in[3];
    float* out = (float*)d_out;

    char* w = (char*)d_ws;
    auto take = [&](size_t bytes) {
        char* p = w;
        w += (bytes + 255) & ~(size_t)255;
        return p;
    };
    int*   deg    = (int*)take((size_t)N_NODES * 4);
    int*   rdeg   = (int*)take((size_t)N_NODES * 4);
    float* dinv   = (float*)take((size_t)N_NODES * 4);
    int*   colcur = (int*)take((size_t)N_NODES * 4);
    int*   colptr = (int*)take((size_t)(N_NODES + 1) * 4);
    int*   col_i  = (int*)take((size_t)NNZ_CAP * 4);
    float* val    = (float*)take((size_t)NNZ_CAP * 4);
    int*   rcolF  = (int*)take((size_t)N_NODES * RSTRIDE * 4);
    float* rlvalF = (float*)take((size_t)N_NODES * RSTRIDE * 4);
    float* sW     = (float*)take((size_t)KCH * FEAT * 4);
    float* sA     = (float*)take((size_t)KCH * N_NODES * 4);
    float* M      = (float*)take((size_t)KCH * N_NODES * FEAT * 4);
    float* B2     = (float*)take((size_t)N_NODES * FEAT * 4);
    float* B3     = (float*)take((size_t)N_NODES * FEAT * 4);
    int*   t2cnt  = (int*)take((size_t)N_NODES * 4);
    unsigned short* t2c = (unsigned short*)take((size_t)N_NODES * T2CAP * 2); // 16 MB
    float* t2v    = (float*)take((size_t)N_NODES * T2CAP * 4);                // 32 MB

    hipMemsetAsync(deg, 0, (size_t)N_NODES * 4, stream);
    k_adj<<<N_NODES / 4, 256, 0, stream>>>(adj, deg, rdeg, rcolF);
    k_scan<<<1, 1024, 0, stream>>>(deg, dinv, colptr, colcur);
    k_vals<<<N_NODES / 4 + 2, 256, 0, stream>>>(dinv, rdeg, rcolF, rlvalF,
                                                colcur, col_i, val, W, sW);
    k_t2<<<N_NODES, TB2, 0, stream>>>(rdeg, rcolF, rlvalF, t2c, t2v, t2cnt, sA);
    k_t3<<<N_NODES / 2, TB3, 0, stream>>>(rdeg, rcolF, rlvalF, t2c, t2v, t2cnt, sA);
    k_cm<<<dim3(N_NODES / 16, KCH), 256, 0, stream>>>(r, sA, sW, W, M);
    k_h1<<<N_NODES / 2, 256, 0, stream>>>(colptr, col_i, val, M, B2);
    k_h2<<<N_NODES / 2, 256, 0, stream>>>(colptr, col_i, val, M, B2, B3);
    k_h3<<<N_NODES / 2, 256, 0, stream>>>(colptr, col_i, val, M, B3, out);
}

// Round 22
// 306.889 us; speedup vs baseline: 1.0731x; 1.0731x over previous
//
#include <hip/hip_runtime.h>
#include <cstdint>
#include <cstddef>

#define N_NODES 4096
#define FEAT 128
#define KCH 4
#define NNZ_CAP (1 << 18)   // col-CSR cap; expected nnz ~65.5K
#define TB2 256             // threads for k_t2 (4 waves -> 8 blocks/CU co-resident)
#define TB3 256             // threads for k_t3 (4 waves -> 8 blocks/CU co-resident)
#define T2CAP 2048          // sparse T2 row stride (expected ~273 nnz/row)
#define RSTRIDE 96          // fixed row-list stride (max out-degree ~40 expected)

// OpenBLAS sgemm K-panel boundaries for K=4096, GEMM_Q=384 (level3.c balancing):
// 0,384,768,1152,1536,1920,2304,2688,3072,3456,3776,4096
__device__ __forceinline__ int panel_of(int p) {
    return p < 3456 ? (p / 384) : (p < 3776 ? 9 : 10);
}

// ---- Single adjacency pass (float4 vectorized): per-row ascending column lists
//      (fixed stride) + out-degree + in-degree counts. One 64 MB read, 1 KB/wave-access.
__global__ __launch_bounds__(256) void k_adj(const float* __restrict__ adj,
                                             int* __restrict__ deg,
                                             int* __restrict__ rdeg,
                                             int* __restrict__ rcolF) {
    int row = (blockIdx.x * 256 + threadIdx.x) >> 6;   // wave per row
    int lane = threadIdx.x & 63;
    const float4* rowp = (const float4*)(adj + (size_t)row * N_NODES);
    int base = 0;
    for (int it = 0; it < 16; ++it) {
        float4 q = rowp[it * 64 + lane];
        int nib = (q.x != 0.0f) | ((q.y != 0.0f) << 1)
                | ((q.z != 0.0f) << 2) | ((q.w != 0.0f) << 3);
        int cnt = __popc(nib);
        int sc = cnt;                       // inclusive lane prefix of counts
        for (int off = 1; off < 64; off <<= 1) {
            int n = __shfl_up(sc, off);
            if (lane >= off) sc += n;
        }
        int myoff = base + sc - cnt;        // exclusive prefix -> ascending col order
        int x0 = it * 256 + 4 * lane;
        #pragma unroll
        for (int c = 0; c < 4; ++c) {
            if (nib & (1 << c)) {
                if (myoff < RSTRIDE) rcolF[row * RSTRIDE + myoff] = x0 + c;
                atomicAdd(&deg[x0 + c], 1);
                ++myoff;
            }
        }
        base += __shfl(sc, 63);             // wave total
    }
    if (lane == 0) rdeg[row] = (base > RSTRIDE) ? RSTRIDE : base;
}

// ---- Scan: dinv = correctly-rounded fp32 d^-0.5; colptr/colcur from deg.
//      Wave-shuffle scan (2 barriers).
__global__ __launch_bounds__(1024) void k_scan(const int* __restrict__ deg,
                                               float* __restrict__ dinv,
                                               int* __restrict__ colptr,
                                               int* __restrict__ colcur) {
    __shared__ int wsum[16];
    __shared__ int wbase[16];
    int t = threadIdx.x;
    int lane = t & 63, wv = t >> 6;
    int v[4]; int s = 0;
    for (int c = 0; c < 4; ++c) {
        int idx = t * 4 + c;
        int di = deg[idx];
        v[c] = di;
        s += di;
        float dc = fmaxf((float)di, 1.0f);
        dinv[idx] = (float)(1.0 / sqrt((double)dc));  // correctly-rounded fp32 x^-0.5
    }
    int sc = s;
    for (int off = 1; off < 64; off <<= 1) {
        int n = __shfl_up(sc, off);
        if (lane >= off) sc += n;
    }
    if (lane == 63) wsum[wv] = sc;
    __syncthreads();
    if (t == 0) {
        int b = 0;
        for (int q2 = 0; q2 < 16; ++q2) { wbase[q2] = b; b += wsum[q2]; }
    }
    __syncthreads();
    int base = wbase[wv] + sc - s;   // exclusive prefix over threads
    for (int c = 0; c < 4; ++c) {
        int idx = t * 4 + c;
        colptr[idx] = base; colcur[idx] = base;
        base += v[c];
    }
    if (t == 1023) colptr[N_NODES] = base;
}

// ---- Values pass + fused sW: blocks [0,1024) do rlvalF/col-CSR; blocks 1024-1025 do
//      sW[k][j] = fp32 sequential sum over y (numpy strided-axis reduce order).
__global__ __launch_bounds__(256) void k_vals(const float* __restrict__ dinv,
                                              const int* __restrict__ rdeg,
                                              const int* __restrict__ rcolF,
                                              float* __restrict__ rlvalF,
                                              int* __restrict__ colcur,
                                              int* __restrict__ col_i,
                                              float* __restrict__ val,
                                              const float* __restrict__ W,
                                              float* __restrict__ sW) {
    if (blockIdx.x >= N_NODES / 4) {
        int tid = (blockIdx.x - N_NODES / 4) * 256 + threadIdx.x;  // 0..511
        int k = tid >> 7, j = tid & 127;
        float s = 0.f;
        for (int y = 0; y < FEAT; ++y)
            s += fabsf(W[(size_t)j * (KCH * FEAT) + k * FEAT + y]);
        sW[k * FEAT + j] = s;
        return;
    }
    int row = (blockIdx.x * 256 + threadIdx.x) >> 6;
    int lane = threadIdx.x & 63;
    int n = rdeg[row];
    float di = dinv[row];
    for (int e = lane; e < n; e += 64) {
        int x = rcolF[row * RSTRIDE + e];
        float dv = di * dinv[x];
        rlvalF[row * RSTRIDE + e] = -dv;
        int ec = atomicAdd(&colcur[x], 1);
        if (ec < NNZ_CAP) { col_i[ec] = row; val[ec] = dv; }
    }
}

// ---- numpy pairwise_sum over 4096 contiguous fp32 (bitwise replication); needs >=256 thr
__device__ __forceinline__ float np_pairwise_4096(const float* __restrict__ row,
                                                  float* r256, float* leaf,
                                                  float* bc, int t) {
    if (t < 256) {
        int L = t >> 3, j = t & 7;
        const float* p = row + L * 128 + j;
        float a = p[0];
        #pragma unroll
        for (int q = 1; q < 16; ++q) a += p[8 * q];
        r256[t] = a;
    }
    __syncthreads();
    if (t < 32) {
        const float* rr = r256 + t * 8;
        leaf[t] = ((rr[0] + rr[1]) + (rr[2] + rr[3])) + ((rr[4] + rr[5]) + (rr[6] + rr[7]));
    }
    __syncthreads();
    if (t == 0) {
        float v[32];
        #pragma unroll
        for (int q = 0; q < 32; ++q) v[q] = leaf[q];
        #pragma unroll
        for (int w = 16; w >= 1; w >>= 1)
            #pragma unroll
            for (int q = 0; q < 16; ++q)
                if (q < w) v[q] = v[2 * q] + v[2 * q + 1];
        bc[0] = v[0];
    }
    __syncthreads();
    float res = bc[0];
    __syncthreads();
    return res;
}

// ---- k_t2 (bit-exact, TB2=256, no LDS staging, 8 blocks/CU): s1 = pairwise(L-row);
//      G = (L@L)_row with OpenBLAS kc-panels (q-ascending direct-global fmaf scatter,
//      barrier per q; synthetic diag t==0; float4 register panel fold). T2 = fl(2G-I);
//      s2 = pairwise; sparse emission (ascending col) into SPLIT ushort/float arrays.
__global__ __launch_bounds__(TB2) void k_t2(const int* __restrict__ rdeg,
                                            const int* __restrict__ rcolF,
                                            const float* __restrict__ rlvalF,
                                            unsigned short* __restrict__ t2c,
                                            float* __restrict__ t2v,
                                            int* __restrict__ t2cnt,
                                            float* __restrict__ sA) {
    __shared__ float gp[N_NODES];     // panel partial; later T2 dense row
    __shared__ int   pcol[64];
    __shared__ float pLip[64];
    __shared__ int   pnn[64];
    __shared__ int   ssplit;
    __shared__ float r256[256], leaf[32], bc[1];
    __shared__ int   wtot[4], wbase[4];
    int t = threadIdx.x;
    int i = blockIdx.x;
    int rp = i * RSTRIDE;
    int ol = rdeg[i];                 // out-degree
    int cnt = ol + 1;                 // + diagonal
    if (cnt > 64) cnt = 64;
    if (t == 0) ssplit = 0;
    __syncthreads();
    if (t < ol && rcolF[rp + t] < i) atomicAdd(&ssplit, 1);
    __syncthreads();
    int split = ssplit;
    if (t < cnt) {
        int col; float lip;
        if (t < split)       { col = rcolF[rp + t];     lip = rlvalF[rp + t]; }
        else if (t == split) { col = i;                 lip = 1.0f; }
        else                 { col = rcolF[rp + t - 1]; lip = rlvalF[rp + t - 1]; }
        pcol[t] = col; pLip[t] = lip; pnn[t] = rdeg[col];
    }
    float4* gp4 = (float4*)gp;
    const float4 z4 = make_float4(0.f, 0.f, 0.f, 0.f);
    #pragma unroll
    for (int u2 = 0; u2 < 4; ++u2) gp4[t + u2 * TB2] = z4;
    __syncthreads();
    // ---- s1: build dense L-row(i) in gp, pairwise, sparse-clear
    for (int e = t; e < ol; e += TB2) gp[rcolF[rp + e]] = rlvalF[rp + e];
    if (t == 0) gp[i] = 1.0f;
    __syncthreads();
    float s1 = np_pairwise_4096(gp, r256, leaf, bc, t);
    for (int e = t; e < ol; e += TB2) gp[rcolF[rp + e]] = 0.0f;
    if (t == 0) gp[i] = 0.0f;
    __syncthreads();
    // ---- G = (L@L) row i
    float tot[16];
    #pragma unroll
    for (int u = 0; u < 16; ++u) tot[u] = 0.0f;
    int q = 0;
    while (q < cnt) {
        {
            float lv = pLip[q];
            int p = pcol[q];
            int nn = pnn[q];
            int b = p * RSTRIDE;
            for (int e = t; e < nn; e += TB2)
                gp[rcolF[b + e]] = fmaf(lv, rlvalF[b + e], gp[rcolF[b + e]]);
            if (t == 0) gp[p] = fmaf(lv, 1.0f, gp[p]);   // synthetic diagonal (p not in row)
            __syncthreads();
        }
        ++q;
        if (q == cnt || panel_of(pcol[q]) != panel_of(pcol[q - 1])) {
            #pragma unroll
            for (int u2 = 0; u2 < 4; ++u2) {
                int idx = t + u2 * TB2;
                float4 b = gp4[idx];
                tot[4 * u2 + 0] = tot[4 * u2 + 0] + b.x;
                tot[4 * u2 + 1] = tot[4 * u2 + 1] + b.y;
                tot[4 * u2 + 2] = tot[4 * u2 + 2] + b.z;
                tot[4 * u2 + 3] = tot[4 * u2 + 3] + b.w;
                gp4[idx] = z4;
            }
            __syncthreads();
        }
    }
    // T2 entries fl(2G - I), dense store from registers (x = 4t + 1024*u2 + c)
    #pragma unroll
    for (int u2 = 0; u2 < 4; ++u2) {
        int xb = 4 * t + 1024 * u2;
        float4 v;
        v.x = 2.0f * tot[4 * u2 + 0] - (xb + 0 == i ? 1.0f : 0.0f);
        v.y = 2.0f * tot[4 * u2 + 1] - (xb + 1 == i ? 1.0f : 0.0f);
        v.z = 2.0f * tot[4 * u2 + 2] - (xb + 2 == i ? 1.0f : 0.0f);
        v.w = 2.0f * tot[4 * u2 + 3] - (xb + 3 == i ? 1.0f : 0.0f);
        gp4[t + u2 * TB2] = v;
    }
    __syncthreads();
    float s2 = np_pairwise_4096(gp, r256, leaf, bc, t);
    // ---- sparse emission (ascending col): thread t owns x in [16t, 16t+16)
    float ev[16];
    #pragma unroll
    for (int u2 = 0; u2 < 4; ++u2) {
        float4 e4 = gp4[4 * t + u2];
        ev[4 * u2 + 0] = e4.x; ev[4 * u2 + 1] = e4.y;
        ev[4 * u2 + 2] = e4.z; ev[4 * u2 + 3] = e4.w;
    }
    int cl = 0;
    #pragma unroll
    for (int u = 0; u < 16; ++u) cl += (ev[u] != 0.0f);
    int lane = t & 63, wv = t >> 6;
    int sc = cl;
    for (int off = 1; off < 64; off <<= 1) {
        int n = __shfl_up(sc, off);
        if (lane >= off) sc += n;
    }
    if (lane == 63) wtot[wv] = sc;
    __syncthreads();
    if (t == 0) {
        int b = 0;
        for (int wq = 0; wq < 4; ++wq) { wbase[wq] = b; b += wtot[wq]; }
        t2cnt[i] = (b > T2CAP) ? T2CAP : b;
    }
    __syncthreads();
    int pos = wbase[wv] + sc - cl;
    unsigned short* dstc = t2c + (size_t)i * T2CAP;
    float* dstv = t2v + (size_t)i * T2CAP;
    #pragma unroll
    for (int u = 0; u < 16; ++u) {
        if (ev[u] != 0.0f) {
            if (pos < T2CAP) { dstc[pos] = (unsigned short)(t * 16 + u); dstv[pos] = ev[u]; }
            ++pos;
        }
    }
    if (t == 0) {
        sA[0 * N_NODES + i] = 1.0f;
        sA[1 * N_NODES + i] = s1;
        sA[2 * N_NODES + i] = s2;
    }
}

// ---- k_t3 (bit-exact, TB3=256, 8 blocks/CU; split ushort/float T2 reads): direct
//      global scatter per q (barrier preserves q-order); float4 register panel fold.
//      T3 = fl(2H - T1); s3 = pairwise.
__global__ __launch_bounds__(TB3) void k_t3(const int* __restrict__ rdeg,
                                            const int* __restrict__ rcolF,
                                            const float* __restrict__ rlvalF,
                                            const unsigned short* __restrict__ t2c,
                                            const float* __restrict__ t2v,
                                            const int* __restrict__ t2cnt,
                                            float* __restrict__ sA) {
    __shared__ float gp[N_NODES];     // panel partial, then final T3 row
    __shared__ int   pcol[64];
    __shared__ float pLip[64];
    __shared__ int   pnn[64];
    __shared__ int   ssplit;
    __shared__ float r256[256], leaf[32], bc[1];
    int t = threadIdx.x;
    int i = blockIdx.x;
    int rp = i * RSTRIDE;
    int ol = rdeg[i];
    int cnt = ol + 1;
    if (cnt > 64) cnt = 64;
    if (t == 0) ssplit = 0;
    __syncthreads();
    if (t < ol && rcolF[rp + t] < i) atomicAdd(&ssplit, 1);
    __syncthreads();
    int split = ssplit;
    if (t < cnt) {
        int col; float lip;
        if (t < split)       { col = rcolF[rp + t];     lip = rlvalF[rp + t]; }
        else if (t == split) { col = i;                  lip = 1.0f; }
        else                 { col = rcolF[rp + t - 1];  lip = rlvalF[rp + t - 1]; }
        pcol[t] = col; pLip[t] = lip; pnn[t] = t2cnt[col];
    }
    float4* gp4 = (float4*)gp;
    const float4 z4 = make_float4(0.f, 0.f, 0.f, 0.f);
    #pragma unroll
    for (int u2 = 0; u2 < 4; ++u2) gp4[t + u2 * TB3] = z4;
    __syncthreads();   // publishes pcol/pLip/pnn and zeroed gp
    float tot[16];
    #pragma unroll
    for (int u = 0; u < 16; ++u) tot[u] = 0.0f;
    int q = 0;
    while (q < cnt) {
        {
            float lv = pLip[q];
            int nn = pnn[q];
            const unsigned short* spc = t2c + (size_t)pcol[q] * T2CAP;
            const float* spv = t2v + (size_t)pcol[q] * T2CAP;
            for (int e = t; e < nn; e += TB3) {
                int x = spc[e];
                gp[x] = fmaf(lv, spv[e], gp[x]);
            }
            __syncthreads();
        }
        ++q;
        if (q == cnt || panel_of(pcol[q]) != panel_of(pcol[q - 1])) {
            #pragma unroll
            for (int u2 = 0; u2 < 4; ++u2) {
                int idx = t + u2 * TB3;
                float4 b = gp4[idx];
                tot[4 * u2 + 0] = tot[4 * u2 + 0] + b.x;
                tot[4 * u2 + 1] = tot[4 * u2 + 1] + b.y;
                tot[4 * u2 + 2] = tot[4 * u2 + 2] + b.z;
                tot[4 * u2 + 3] = tot[4 * u2 + 3] + b.w;
                gp4[idx] = z4;
            }
            __syncthreads();
        }
    }
    #pragma unroll
    for (int u2 = 0; u2 < 4; ++u2) {
        float4 v;
        v.x = 2.0f * tot[4 * u2 + 0];
        v.y = 2.0f * tot[4 * u2 + 1];
        v.z = 2.0f * tot[4 * u2 + 2];
        v.w = 2.0f * tot[4 * u2 + 3];
        gp4[t + u2 * TB3] = v;       // exact x2
    }
    __syncthreads();
    for (int e = t; e < ol; e += TB3) { int x = rcolF[rp + e]; gp[x] = gp[x] - rlvalF[rp + e]; }
    if (t == 0) gp[i] = gp[i] - 1.0f;
    __syncthreads();
    float s3 = np_pairwise_4096(gp, r256, leaf, bc, t);
    if (t == 0) sA[3 * N_NODES + i] = s3;
}

// ---- Fused c + M (16 rows/block -> 1024 blocks): c[i,j] = r[i,j]/denom (exact k_c
//      arithmetic: non-contracted, ascending-k mul then add);
//      M_k[i,y] = sum_j c[i,j]*|W[j,k*128+y]|
__global__ __launch_bounds__(256) void k_cm(const float* __restrict__ r,
                                            const float* __restrict__ sA,
                                            const float* __restrict__ sW,
                                            const float* __restrict__ W,
                                            float* __restrict__ M) {
#pragma clang fp contract(off)
    __shared__ float cl[16][FEAT];
    int k = blockIdx.y;
    int ib = blockIdx.x * 16;
    int tx = threadIdx.x;
    int y = tx & 127, half = tx >> 7;
    for (int m = tx; m < 16 * FEAT; m += 256) {
        int i = ib + (m >> 7), j = m & 127;
        float denom = 0.0f;
        #pragma unroll
        for (int k2 = 0; k2 < KCH; ++k2) {
            float p = sA[k2 * N_NODES + i] * sW[k2 * FEAT + j];
            denom = denom + p;
        }
        cl[m >> 7][m & 127] = r[(size_t)i * FEAT + j] / denom;
    }
    __syncthreads();
    float acc[8];
    #pragma unroll
    for (int u = 0; u < 8; ++u) acc[u] = 0.0f;
    for (int j = 0; j < FEAT; ++j) {
        float a = fabsf(W[(size_t)j * (KCH * FEAT) + k * FEAT + y]);
        #pragma unroll
        for (int u = 0; u < 8; ++u) acc[u] += a * cl[half * 8 + u][j];
    }
    #pragma unroll
    for (int u = 0; u < 8; ++u)
        M[(size_t)k * N_NODES * FEAT + (size_t)(ib + half * 8 + u) * FEAT + y] = acc[u];
}

// ---- Horner output chain: out = M0 - M2 + Lap(M1 - 3M3 + Lap(2M2 + Lap(4M3))),
//      Lap(A) = A - D^T A. Three gather applications total.
// h1: B2 = 2M2 + 4*(M3 - D'M3)
__global__ void k_h1(const int* __restrict__ colptr, const int* __restrict__ col_i,
                     const float* __restrict__ val, const float* __restrict__ M,
                     float* __restrict__ B2) {
    int x = blockIdx.x * 2 + (threadIdx.x >> 7);
    int y = threadIdx.x & 127;
    const float* M2 = M + (size_t)2 * N_NODES * FEAT;
    const float* M3 = M + (size_t)3 * N_NODES * FEAT;
    int e0 = colptr[x], e1 = colptr[x + 1];
    if (e1 > NNZ_CAP) e1 = NNZ_CAP;
    float g = 0.0f;
    for (int e = e0; e < e1; ++e)
        g += val[e] * M3[(size_t)col_i[e] * FEAT + y];
    size_t o = (size_t)x * FEAT + y;
    B2[o] = 2.0f * M2[o] + 4.0f * (M3[o] - g);
}

// h2: B3 = (M1 - 3M3) + (B2 - D'B2)
__global__ void k_h2(const int* __restrict__ colptr, const int* __restrict__ col_i,
                     const float* __restrict__ val, const float* __restrict__ M,
                     const float* __restrict__ B2, float* __restrict__ B3) {
    int x = blockIdx.x * 2 + (threadIdx.x >> 7);
    int y = threadIdx.x & 127;
    const float* M1 = M + (size_t)N_NODES * FEAT;
    const float* M3 = M + (size_t)3 * N_NODES * FEAT;
    int e0 = colptr[x], e1 = colptr[x + 1];
    if (e1 > NNZ_CAP) e1 = NNZ_CAP;
    float g = 0.0f;
    for (int e = e0; e < e1; ++e)
        g += val[e] * B2[(size_t)col_i[e] * FEAT + y];
    size_t o = (size_t)x * FEAT + y;
    B3[o] = (M1[o] - 3.0f * M3[o]) + (B2[o] - g);
}

// h3: out = (M0 - M2) + (B3 - D'B3)
__global__ void k_h3(const int* __restrict__ colptr, const int* __restrict__ col_i,
                     const float* __restrict__ val, const float* __restrict__ M,
                     const float* __restrict__ B3, float* __restrict__ out) {
    int x = blockIdx.x * 2 + (threadIdx.x >> 7);
    int y = threadIdx.x & 127;
    const float* M0 = M;
    const float* M2 = M + (size_t)2 * N_NODES * FEAT;
    int e0 = colptr[x], e1 = colptr[x + 1];
    if (e1 > NNZ_CAP) e1 = NNZ_CAP;
    float g = 0.0f;
    for (int e = e0; e < e1; ++e)
        g += val[e] * B3[(size_t)col_i[e] * FEAT + y];
    size_t o = (size_t)x * FEAT + y;
    out[o] = (M0[o] - M2[o]) + (B3[o] - g);
}

extern "C" void kernel_launch(void* const* d_in, const int* in_sizes, int n_in,
                              void* d_out, int out_size, void* d_ws, size_t ws_size,
                              hipStream_t stream) {
    const float* r   = (const float*)d_in[1];
    const float* adj = (const float*)d_in[2];
    const float* W   = (const float*)d_in[3];
    float* out = (float*)d_out;

    char* w = (char*)d_ws;
    auto take = [&](size_t bytes) {
        char* p = w;
        w += (bytes + 255) & ~(size_t)255;
        return p;
    };
    int*   deg    = (int*)take((size_t)N_NODES * 4);
    int*   rdeg   = (int*)take((size_t)N_NODES * 4);
    float* dinv   = (float*)take((size_t)N_NODES * 4);
    int*   colcur = (int*)take((size_t)N_NODES * 4);
    int*   colptr = (int*)take((size_t)(N_NODES + 1) * 4);
    int*   col_i  = (int*)take((size_t)NNZ_CAP * 4);
    float* val    = (float*)take((size_t)NNZ_CAP * 4);
    int*   rcolF  = (int*)take((size_t)N_NODES * RSTRIDE * 4);
    float* rlvalF = (float*)take((size_t)N_NODES * RSTRIDE * 4);
    float* sW     = (float*)take((size_t)KCH * FEAT * 4);
    float* sA     = (float*)take((size_t)KCH * N_NODES * 4);
    float* M      = (float*)take((size_t)KCH * N_NODES * FEAT * 4);
    float* B2     = (float*)take((size_t)N_NODES * FEAT * 4);
    float* B3     = (float*)take((size_t)N_NODES * FEAT * 4);
    int*   t2cnt  = (int*)take((size_t)N_NODES * 4);
    unsigned short* t2c = (unsigned short*)take((size_t)N_NODES * T2CAP * 2); // 16 MB
    float* t2v    = (float*)take((size_t)N_NODES * T2CAP * 4);                // 32 MB

    hipMemsetAsync(deg, 0, (size_t)N_NODES * 4, stream);
    k_adj<<<N_NODES / 4, 256, 0, stream>>>(adj, deg, rdeg, rcolF);
    k_scan<<<1, 1024, 0, stream>>>(deg, dinv, colptr, colcur);
    k_vals<<<N_NODES / 4 + 2, 256, 0, stream>>>(dinv, rdeg, rcolF, rlvalF,
                                                colcur, col_i, val, W, sW);
    k_t2<<<N_NODES, TB2, 0, stream>>>(rdeg, rcolF, rlvalF, t2c, t2v, t2cnt, sA);
    k_t3<<<N_NODES, TB3, 0, stream>>>(rdeg, rcolF, rlvalF, t2c, t2v, t2cnt, sA);
    k_cm<<<dim3(N_NODES / 16, KCH), 256, 0, stream>>>(r, sA, sW, W, M);
    k_h1<<<N_NODES / 2, 256, 0, stream>>>(colptr, col_i, val, M, B2);
    k_h2<<<N_NODES / 2, 256, 0, stream>>>(colptr, col_i, val, M, B2, B3);
    k_h3<<<N_NODES / 2, 256, 0, stream>>>(colptr, col_i, val, M, B3, out);
}